// Round 1
// baseline (310.872 us; speedup 1.0000x reference)
//
#include <hip/hip_runtime.h>
#include <hip/hip_bf16.h>

// SignAttention on MI355X, round 1.
// Math: per (b,h): scores = Wk_h @ ((X_b @ Wq_h) @ X_b)  (reassociated, 3.3x fewer FLOPs)
//       attn = chunk128-softmax(scores/32); O = V_bh @ attn; Y = Wr @ O + br.
// All GEMMs bf16-MFMA (16x16x32), NT layout (A: MxK row-major, B: NxK row-major).

using bf16x8 = __attribute__((ext_vector_type(8))) __bf16;
using f32x4  = __attribute__((ext_vector_type(4))) float;
using s16x4  = __attribute__((ext_vector_type(4))) short;

static __device__ __forceinline__ short f2b(float f) {  // fp32 -> bf16, RNE
  union { float f; unsigned u; } v; v.f = f;
  unsigned r = v.u + 0x7fffu + ((v.u >> 16) & 1u);
  return (short)(r >> 16);
}

#define MFMA16(a, b, c) __builtin_amdgcn_mfma_f32_16x16x32_bf16((a), (b), (c), 0, 0, 0)

// ---------------- elementwise fp32 -> bf16 ----------------
__global__ __launch_bounds__(256) void cvt_bf16(const float* __restrict__ in,
                                                short* __restrict__ out, int n) {
  int i = (blockIdx.x * 256 + threadIdx.x) * 4;
  if (i >= n) return;
  float4 v = *(const float4*)(in + i);
  s16x4 s = { f2b(v.x), f2b(v.y), f2b(v.z), f2b(v.w) };
  *(s16x4*)(out + i) = s;
}

// ------- 64x64-tile convert (+optional plain bf16 copy) + transpose -------
__global__ __launch_bounds__(256) void tcvt(const float* __restrict__ in,
    short* __restrict__ outP, short* __restrict__ outT,
    int R, int C, long inB, long pB, long tB)
{
  __shared__ short tile[64][68];
  long bz = blockIdx.z;
  const float* src = in + bz * inB;
  int r0 = blockIdx.y * 64, c0 = blockIdx.x * 64;
  int t = threadIdx.x;
  int r = t >> 2, cq = (t & 3) * 16;
  #pragma unroll
  for (int e = 0; e < 16; e += 4) {
    float4 v = *(const float4*)(&src[(long)(r0 + r) * C + (c0 + cq + e)]);
    s16x4 s = { f2b(v.x), f2b(v.y), f2b(v.z), f2b(v.w) };
    *(s16x4*)(&tile[r][cq + e]) = s;
    if (outP) *(s16x4*)(&outP[bz * pB + (long)(r0 + r) * C + (c0 + cq + e)]) = s;
  }
  __syncthreads();
  int tr = t >> 2, re = (t & 3) * 16;
  short tmp[16];
  #pragma unroll
  for (int e = 0; e < 16; ++e) tmp[e] = tile[re + e][tr];
  short* dst = &outT[bz * tB + (long)(c0 + tr) * R + (r0 + re)];
  #pragma unroll
  for (int e = 0; e < 16; e += 4) *(s16x4*)(&dst[e]) = *(const s16x4*)(&tmp[e]);
}

// ---------------- generic batched NT GEMM, 128x128 tile, BK=64 ----------------
// A: MxK row-major (lda), B: NxK row-major (ldb), C: MxN (ldc). bf16 in, bf16/f32 out.
template<bool F32OUT>
__global__ __launch_bounds__(256) void gemm_nt(
    const short* __restrict__ A, const short* __restrict__ B,
    void* __restrict__ C, const float* __restrict__ bias,
    int M, int N, int K, int lda, int ldb, int ldc,
    long aSB, long aSH, long bSB, long bSH, long cSB, long cSH, int nh)
{
  int batch = blockIdx.z;
  int hb = batch % nh, bb = batch / nh;
  const short* Ab = A + bb * aSB + hb * aSH;
  const short* Bb = B + bb * bSB + hb * bSH;
  long cOff = bb * cSB + hb * cSH;
  int m0 = blockIdx.y * 128, n0 = blockIdx.x * 128;
  __shared__ short As[128 * 72];   // pad 64->72: row stride 144B (16B-aligned, bank step 4)
  __shared__ short Bs[128 * 72];
  int t = threadIdx.x;
  int lane = t & 63, wid = t >> 6;
  int wm = (wid >> 1) * 64, wn = (wid & 1) * 64;
  int rl = lane & 15, q = lane >> 4;
  f32x4 acc[4][4] = {};
  for (int k0 = 0; k0 < K; k0 += 64) {
    __syncthreads();
    #pragma unroll
    for (int it = 0; it < 4; ++it) {
      int e = (t + 256 * it) * 8;
      int row = e >> 6, col = e & 63;
      *(int4*)(&As[row * 72 + col]) = *(const int4*)(&Ab[(long)(m0 + row) * lda + (k0 + col)]);
      *(int4*)(&Bs[row * 72 + col]) = *(const int4*)(&Bb[(long)(n0 + row) * ldb + (k0 + col)]);
    }
    __syncthreads();
    #pragma unroll
    for (int kt = 0; kt < 2; ++kt) {
      int kq = kt * 32 + q * 8;
      bf16x8 af[4], bfv[4];
      #pragma unroll
      for (int mi = 0; mi < 4; ++mi) af[mi] = *(const bf16x8*)(&As[(wm + 16 * mi + rl) * 72 + kq]);
      #pragma unroll
      for (int ni = 0; ni < 4; ++ni) bfv[ni] = *(const bf16x8*)(&Bs[(wn + 16 * ni + rl) * 72 + kq]);
      #pragma unroll
      for (int mi = 0; mi < 4; ++mi)
        #pragma unroll
        for (int ni = 0; ni < 4; ++ni)
          acc[mi][ni] = MFMA16(af[mi], bfv[ni], acc[mi][ni]);
    }
  }
  #pragma unroll
  for (int mi = 0; mi < 4; ++mi)
    #pragma unroll
    for (int ni = 0; ni < 4; ++ni)
      #pragma unroll
      for (int r = 0; r < 4; ++r) {
        int row = m0 + wm + 16 * mi + 4 * q + r;
        int col = n0 + wn + 16 * ni + rl;
        float val = acc[mi][ni][r];
        if (F32OUT) {
          ((float*)C)[cOff + (long)row * ldc + col] = val + (bias ? bias[row] : 0.f);
        } else {
          ((short*)C)[cOff + (long)row * ldc + col] = f2b(val);
        }
      }
}

// ---------------- fused S = Wk_h@G, chunk-softmax, O^T = attn^T @ V^T ----------------
// grid = 512 blocks: (b,h,c); 256 threads = 4 waves; each wave owns 32 score-rows.
__global__ __launch_bounds__(256) void attn_fused(
    const short* __restrict__ Wk, const short* __restrict__ GT,
    const short* __restrict__ V, short* __restrict__ OT)
{
  __shared__ short smem[18432];
  short* As = smem;            // [128][72]  Wk tile
  short* Bs = smem + 9216;     // [128][72]  GT tile
  short* aT = smem;            // [128][136] attn^T  (aliases As/Bs, phase-separated)
  int blk = blockIdx.x;
  int c = blk & 7, h = (blk >> 3) & 7, b = blk >> 6;
  int t = threadIdx.x, lane = t & 63, w = t >> 6;
  int rl = lane & 15, q = lane >> 4;
  const short* Wkh = Wk + (long)(h * 1024) * 256;
  const short* GTc = GT + ((long)(b * 8 + h) * 1024 + c * 128) * 256;
  const short* Vb  = V + (long)(b * 512 + h * 64) * 1024;
  f32x4 ot[2][4] = {};
  const float SC = 1.4426950408889634f / 32.0f;  // log2(e)/sqrt(dk)

  for (int ri = 0; ri < 8; ++ri) {          // 8 row-tiles of 128 score rows
    f32x4 s[2][8] = {};
    for (int k0 = 0; k0 < 256; k0 += 64) {  // S = Wk_h[rows] @ G_c, K=256
      __syncthreads();
      #pragma unroll
      for (int it = 0; it < 4; ++it) {
        int e = (t + 256 * it) * 8;
        int row = e >> 6, col = e & 63;
        *(int4*)(&As[row * 72 + col]) = *(const int4*)(&Wkh[(long)(ri * 128 + row) * 256 + (k0 + col)]);
        *(int4*)(&Bs[row * 72 + col]) = *(const int4*)(&GTc[(long)row * 256 + (k0 + col)]);
      }
      __syncthreads();
      #pragma unroll
      for (int kt = 0; kt < 2; ++kt) {
        int kq = kt * 32 + q * 8;
        bf16x8 af[2], bfv[8];
        af[0] = *(const bf16x8*)(&As[(w * 32 + rl) * 72 + kq]);
        af[1] = *(const bf16x8*)(&As[(w * 32 + 16 + rl) * 72 + kq]);
        #pragma unroll
        for (int ni = 0; ni < 8; ++ni) bfv[ni] = *(const bf16x8*)(&Bs[(16 * ni + rl) * 72 + kq]);
        #pragma unroll
        for (int mi = 0; mi < 2; ++mi)
          #pragma unroll
          for (int ni = 0; ni < 8; ++ni)
            s[mi][ni] = MFMA16(af[mi], bfv[ni], s[mi][ni]);
      }
    }
    // ---- softmax over the 128 columns, per row (row = 32w+16mi+4q+r) ----
    float mx[2][4], sm[2][4], rc[2][4];
    #pragma unroll
    for (int mi = 0; mi < 2; ++mi)
      #pragma unroll
      for (int r = 0; r < 4; ++r) {
        float m = s[mi][0][r];
        #pragma unroll
        for (int ni = 1; ni < 8; ++ni) m = fmaxf(m, s[mi][ni][r]);
        mx[mi][r] = m;
      }
    #pragma unroll
    for (int msk = 1; msk < 16; msk <<= 1)
      #pragma unroll
      for (int mi = 0; mi < 2; ++mi)
        #pragma unroll
        for (int r = 0; r < 4; ++r)
          mx[mi][r] = fmaxf(mx[mi][r], __shfl_xor(mx[mi][r], msk, 64));
    #pragma unroll
    for (int mi = 0; mi < 2; ++mi)
      #pragma unroll
      for (int r = 0; r < 4; ++r) sm[mi][r] = 0.f;
    #pragma unroll
    for (int mi = 0; mi < 2; ++mi)
      #pragma unroll
      for (int ni = 0; ni < 8; ++ni)
        #pragma unroll
        for (int r = 0; r < 4; ++r) {
          float p = exp2f((s[mi][ni][r] - mx[mi][r]) * SC);
          s[mi][ni][r] = p;
          sm[mi][r] += p;
        }
    #pragma unroll
    for (int msk = 1; msk < 16; msk <<= 1)
      #pragma unroll
      for (int mi = 0; mi < 2; ++mi)
        #pragma unroll
        for (int r = 0; r < 4; ++r)
          sm[mi][r] += __shfl_xor(sm[mi][r], msk, 64);
    #pragma unroll
    for (int mi = 0; mi < 2; ++mi)
      #pragma unroll
      for (int r = 0; r < 4; ++r) rc[mi][r] = __builtin_amdgcn_rcpf(sm[mi][r]);

    __syncthreads();                       // all S-LDS reads done before alias reuse
    #pragma unroll
    for (int mi = 0; mi < 2; ++mi)
      #pragma unroll
      for (int ni = 0; ni < 8; ++ni) {
        s16x4 pk = { f2b(s[mi][ni][0] * rc[mi][0]), f2b(s[mi][ni][1] * rc[mi][1]),
                     f2b(s[mi][ni][2] * rc[mi][2]), f2b(s[mi][ni][3] * rc[mi][3]) };
        int j  = 16 * ni + rl;
        int iL = 32 * w + 16 * mi + 4 * q;
        *(s16x4*)(&aT[j * 136 + iL]) = pk;   // aT[j][i] = attn[i][j]
      }
    __syncthreads();
    // ---- O^T[j][d] += sum_i attn[i][j] * V[d][i] over this i-tile ----
    #pragma unroll
    for (int kt = 0; kt < 4; ++kt) {
      int kq = kt * 32 + q * 8;
      bf16x8 pa[2], vb[4];
      pa[0] = *(const bf16x8*)(&aT[(32 * w + rl) * 136 + kq]);
      pa[1] = *(const bf16x8*)(&aT[(32 * w + 16 + rl) * 136 + kq]);
      #pragma unroll
      for (int nd = 0; nd < 4; ++nd)
        vb[nd] = *(const bf16x8*)(&Vb[(long)(16 * nd + rl) * 1024 + (ri * 128 + kq)]);
      #pragma unroll
      for (int mi = 0; mi < 2; ++mi)
        #pragma unroll
        for (int nd = 0; nd < 4; ++nd)
          ot[mi][nd] = MFMA16(pa[mi], vb[nd], ot[mi][nd]);
    }
  }
  // epilogue: OT[b][c*128 + j][h*64 + d]
  short* OTb = OT + (long)(b * 1024 + c * 128) * 512 + h * 64;
  #pragma unroll
  for (int mi = 0; mi < 2; ++mi)
    #pragma unroll
    for (int nd = 0; nd < 4; ++nd)
      #pragma unroll
      for (int r = 0; r < 4; ++r) {
        int j = 32 * w + 16 * mi + 4 * q + r;
        int d = 16 * nd + rl;
        OTb[(long)j * 512 + d] = f2b(ot[mi][nd][r]);
      }
}

extern "C" void kernel_launch(void* const* d_in, const int* in_sizes, int n_in,
                              void* d_out, int out_size, void* d_ws, size_t ws_size,
                              hipStream_t stream)
{
  const float* x  = (const float*)d_in[0];
  const float* Wk = (const float*)d_in[1];
  const float* Wq = (const float*)d_in[2];
  const float* Wv = (const float*)d_in[3];
  const float* Wr = (const float*)d_in[4];
  const float* br = (const float*)d_in[5];
  float* out = (float*)d_out;

  char* ws = (char*)d_ws;
  short* Xbf = (short*)(ws + 0);         // [8][256][1024]
  short* XT  = (short*)(ws + 4194304);   // [8][1024][256]
  short* WqT = (short*)(ws + 8388608);   // [256][8192]
  short* Wkb = (short*)(ws + 12582912);  // [8192][256]
  short* Wvb = (short*)(ws + 16777216);  // [512][256]
  short* Wrb = (short*)(ws + 17039360);  // [256][512]
  short* Mb  = (short*)(ws + 17301504);  // [8][8][256][256]
  short* GTb = (short*)(ws + 25690112);  // [8][8][1024][256]  (= G^T per (b,h))
  short* Vbf = (short*)(ws + 59244544);  // [8][512][1024]
  short* OTb = (short*)(ws + 67633152);  // [8][1024][512]     (= O^T per b)

  // converts / transposes
  tcvt<<<dim3(16, 4, 8), 256, 0, stream>>>(x, Xbf, XT, 256, 1024, 262144L, 262144L, 262144L);
  tcvt<<<dim3(4, 128, 1), 256, 0, stream>>>(Wq, nullptr, WqT, 8192, 256, 0L, 0L, 0L);
  cvt_bf16<<<2048, 256, 0, stream>>>(Wk, Wkb, 2097152);
  cvt_bf16<<<128, 256, 0, stream>>>(Wv, Wvb, 131072);
  cvt_bf16<<<128, 256, 0, stream>>>(Wr, Wrb, 131072);

  // M[b,h] = X_b @ Wq_h            (256x256, K=1024)
  gemm_nt<false><<<dim3(2, 2, 64), 256, 0, stream>>>(Xbf, WqT, Mb, nullptr,
      256, 256, 1024, 1024, 8192, 256,
      262144L, 0L, 0L, 1024L, 524288L, 65536L, 8);
  // G^T[b,h] = X_b^T @ M (M as NxK) (1024x256, K=256)
  gemm_nt<false><<<dim3(2, 8, 64), 256, 0, stream>>>(XT, Mb, GTb, nullptr,
      1024, 256, 256, 256, 256, 256,
      262144L, 0L, 524288L, 65536L, 2097152L, 262144L, 8);
  // V[b] = Wv @ X_b                 (512x1024, K=256)
  gemm_nt<false><<<dim3(8, 4, 8), 256, 0, stream>>>(Wvb, XT, Vbf, nullptr,
      512, 1024, 256, 256, 256, 1024,
      0L, 0L, 262144L, 0L, 524288L, 0L, 1);
  // fused scores + chunk-softmax + PV  -> O^T
  attn_fused<<<512, 256, 0, stream>>>(Wkb, GTb, Vbf, OTb);
  // Y[b] = Wr @ O_b + br            (256x1024, K=512) -> d_out fp32
  gemm_nt<true><<<dim3(8, 2, 8), 256, 0, stream>>>(Wrb, OTb, out, br,
      256, 1024, 512, 512, 512, 1024,
      0L, 0L, 524288L, 0L, 262144L, 0L, 1);
}

// Round 3
// 291.419 us; speedup vs baseline: 1.0668x; 1.0668x over previous
//
#include <hip/hip_runtime.h>
#include <hip/hip_bf16.h>

// SignAttention on MI355X, round 3 (= round-2 kernel, resubmitted after
// GPU-acquisition timeout; it never ran).
// Changes vs r1: global_load_lds(16B) staging everywhere, XOR-swizzled LDS
// (pre-swizzled global source, linear LDS write), GT-tile staged once per
// block, Wk double-buffered with prefetch, 64-row wave tiles in attn QK.

using bf16x8 = __attribute__((ext_vector_type(8))) __bf16;
using f32x4  = __attribute__((ext_vector_type(4))) float;
using s16x4  = __attribute__((ext_vector_type(4))) short;

static __device__ __forceinline__ short f2b(float f) {  // fp32 -> bf16, RNE
  union { float f; unsigned u; } v; v.f = f;
  unsigned r = v.u + 0x7fffu + ((v.u >> 16) & 1u);
  return (short)(r >> 16);
}

static __device__ __forceinline__ void gll16(const void* g, void* l) {
  __builtin_amdgcn_global_load_lds(
      (const __attribute__((address_space(1))) void*)g,
      (__attribute__((address_space(3))) void*)l, 16, 0, 0);
}

#define MFMA16(a, b, c) __builtin_amdgcn_mfma_f32_16x16x32_bf16((a), (b), (c), 0, 0, 0)

// ---------------- elementwise fp32 -> bf16 ----------------
__global__ __launch_bounds__(256) void cvt_bf16(const float* __restrict__ in,
                                                short* __restrict__ out, int n) {
  int i = (blockIdx.x * 256 + threadIdx.x) * 4;
  if (i >= n) return;
  float4 v = *(const float4*)(in + i);
  s16x4 s = { f2b(v.x), f2b(v.y), f2b(v.z), f2b(v.w) };
  *(s16x4*)(out + i) = s;
}

// ------- 64x64-tile convert (+optional plain bf16 copy) + transpose -------
__global__ __launch_bounds__(256) void tcvt(const float* __restrict__ in,
    short* __restrict__ outP, short* __restrict__ outT,
    int R, int C, long inB, long pB, long tB)
{
  __shared__ short tile[64][68];
  long bz = blockIdx.z;
  const float* src = in + bz * inB;
  int r0 = blockIdx.y * 64, c0 = blockIdx.x * 64;
  int t = threadIdx.x;
  int r = t >> 2, cq = (t & 3) * 16;
  #pragma unroll
  for (int e = 0; e < 16; e += 4) {
    float4 v = *(const float4*)(&src[(long)(r0 + r) * C + (c0 + cq + e)]);
    s16x4 s = { f2b(v.x), f2b(v.y), f2b(v.z), f2b(v.w) };
    *(s16x4*)(&tile[r][cq + e]) = s;
    if (outP) *(s16x4*)(&outP[bz * pB + (long)(r0 + r) * C + (c0 + cq + e)]) = s;
  }
  __syncthreads();
  int tr = t >> 2, re = (t & 3) * 16;
  short tmp[16];
  #pragma unroll
  for (int e = 0; e < 16; ++e) tmp[e] = tile[re + e][tr];
  short* dst = &outT[bz * tB + (long)(c0 + tr) * R + (r0 + re)];
  #pragma unroll
  for (int e = 0; e < 16; e += 4) *(s16x4*)(&dst[e]) = *(const s16x4*)(&tmp[e]);
}

// ---------------- generic batched NT GEMM, m97 structure ----------------
// A: MxK row-major (lda), B: NxK row-major (ldb), C: MxN (ldc). bf16 in.
// LDS tiles [128][64] linear; content XOR-swizzled (chunk c in row r holds
// global chunk c^(r&7)); staged by global_load_lds dwordx4.
template<bool F32OUT>
__global__ __launch_bounds__(256) void gemm_nt(
    const short* __restrict__ A, const short* __restrict__ B,
    void* __restrict__ C, const float* __restrict__ bias,
    int M, int N, int K, int lda, int ldb, int ldc,
    long aSB, long aSH, long bSB, long bSH, long cSB, long cSH, int nh)
{
  int batch = blockIdx.z;
  int hb = batch % nh, bb = batch / nh;
  const short* Ab = A + bb * aSB + hb * aSH;
  const short* Bb = B + bb * bSB + hb * bSH;
  long cOff = bb * cSB + hb * cSH;
  int m0 = blockIdx.y * 128, n0 = blockIdx.x * 128;
  __shared__ short As[128 * 64];
  __shared__ short Bs[128 * 64];
  int t = threadIdx.x;
  int lane = t & 63, wid = t >> 6;
  int wm = (wid >> 1) * 64, wn = (wid & 1) * 64;
  int rl = lane & 15, q = lane >> 4;
  f32x4 acc[4][4] = {};
  for (int k0 = 0; k0 < K; k0 += 64) {
    __syncthreads();
    #pragma unroll
    for (int j = 0; j < 4; ++j) {
      int g = j * 256 + t;
      int r = g >> 3, cc = g & 7;
      int cs = cc ^ (r & 7);
      gll16(&Ab[(long)(m0 + r) * lda + k0 + cs * 8], (char*)As + (j * 256 + wid * 64) * 16);
      gll16(&Bb[(long)(n0 + r) * ldb + k0 + cs * 8], (char*)Bs + (j * 256 + wid * 64) * 16);
    }
    __syncthreads();
    #pragma unroll
    for (int kt = 0; kt < 2; ++kt) {
      int cq = kt * 4 + q;
      bf16x8 af[4], bfv[4];
      #pragma unroll
      for (int mi = 0; mi < 4; ++mi) {
        int R = wm + 16 * mi + rl;
        af[mi] = *(const bf16x8*)((const char*)As + (R * 8 + (cq ^ (R & 7))) * 16);
      }
      #pragma unroll
      for (int ni = 0; ni < 4; ++ni) {
        int RN = wn + 16 * ni + rl;
        bfv[ni] = *(const bf16x8*)((const char*)Bs + (RN * 8 + (cq ^ (RN & 7))) * 16);
      }
      #pragma unroll
      for (int mi = 0; mi < 4; ++mi)
        #pragma unroll
        for (int ni = 0; ni < 4; ++ni)
          acc[mi][ni] = MFMA16(af[mi], bfv[ni], acc[mi][ni]);
    }
  }
  #pragma unroll
  for (int mi = 0; mi < 4; ++mi)
    #pragma unroll
    for (int ni = 0; ni < 4; ++ni)
      #pragma unroll
      for (int r = 0; r < 4; ++r) {
        int row = m0 + wm + 16 * mi + 4 * q + r;
        int col = n0 + wn + 16 * ni + rl;
        float val = acc[mi][ni][r];
        if (F32OUT) {
          ((float*)C)[cOff + (long)row * ldc + col] = val + (bias ? bias[row] : 0.f);
        } else {
          ((short*)C)[cOff + (long)row * ldc + col] = f2b(val);
        }
      }
}

// ---------------- fused S = Wk_h@G, chunk-softmax, O^T = attn^T @ V^T --------
// Block (b,h,c), 4 waves. LDS: Bs = GT tile [128 j][256 K] staged ONCE (64KB,
// swizzled), A = Wk tile [256 r][32 K] double-buffered (2x16KB, swizzled),
// aT [128 j][128 i] (32KB, swizzled). Outer loop: 4 iters of 256 score rows.
__global__ __launch_bounds__(256, 1) void attn_fused(
    const short* __restrict__ Wk, const short* __restrict__ GT,
    const short* __restrict__ V, short* __restrict__ OT)
{
  __shared__ short smem[65536];           // 128 KiB
  short* Bs  = smem;                      // [128][256]
  short* Ab0 = smem + 32768;              // [256][32]
  short* Ab1 = smem + 40960;              // [256][32]
  short* aT  = smem + 49152;              // [128][128]
  int blk = blockIdx.x;
  int c = blk & 7, h = (blk >> 3) & 7, b = blk >> 6;
  int t = threadIdx.x, lane = t & 63, w = t >> 6;
  int rl = lane & 15, q = lane >> 4;
  const short* Wkh = Wk + (long)(h * 1024) * 256;
  const short* GTc = GT + ((long)(b * 8 + h) * 1024 + c * 128) * 256;
  const short* Vb  = V + (long)(b * 512 + h * 64) * 1024;
  f32x4 ot[2][4] = {};
  const float SC = 1.4426950408889634f / 32.0f;  // log2(e)/sqrt(dk)

  // ---- prologue: stage full GT tile (once) + A(0,0) ----
  #pragma unroll
  for (int j = 0; j < 16; ++j) {
    int g = j * 256 + t;
    int r = g >> 5, cc = g & 31;
    int cs = cc ^ (r & 7);
    gll16(&GTc[(long)r * 256 + cs * 8], (char*)Bs + (j * 256 + w * 64) * 16);
  }
  {
    #pragma unroll
    for (int j = 0; j < 4; ++j) {
      int g = j * 256 + t;
      int r = g >> 2, cc = g & 3;
      int cs = cc ^ ((r >> 1) & 3);
      gll16(&Wkh[(long)r * 256 + cs * 8], (char*)Ab0 + (j * 256 + w * 64) * 16);
    }
  }
  __syncthreads();

  short* Acur = Ab0;
  short* Anxt = Ab1;
  for (int o = 0; o < 4; ++o) {
    f32x4 s[4][8] = {};
    for (int k0i = 0; k0i < 8; ++k0i) {
      int k0 = k0i * 32;
      // prefetch next A slab into the other buffer
      int nRow = -1, nK = 0;
      if (k0i < 7)      { nRow = o * 256;      nK = k0 + 32; }
      else if (o < 3)   { nRow = (o + 1) * 256; nK = 0; }
      if (nRow >= 0) {
        #pragma unroll
        for (int j = 0; j < 4; ++j) {
          int g = j * 256 + t;
          int r = g >> 2, cc = g & 3;
          int cs = cc ^ ((r >> 1) & 3);
          gll16(&Wkh[(long)(nRow + r) * 256 + nK + cs * 8],
                (char*)Anxt + (j * 256 + w * 64) * 16);
        }
      }
      // compute this K=32 slab
      bf16x8 af[4], bv[8];
      #pragma unroll
      for (int mi = 0; mi < 4; ++mi) {
        int R = w * 64 + 16 * mi + rl;
        af[mi] = *(const bf16x8*)((const char*)Acur + (R * 4 + (q ^ ((R >> 1) & 3))) * 16);
      }
      #pragma unroll
      for (int ni = 0; ni < 8; ++ni) {
        int Rj = 16 * ni + rl;
        int cb = (k0 >> 3) + q;
        bv[ni] = *(const bf16x8*)((const char*)Bs + (Rj * 32 + (cb ^ (Rj & 7))) * 16);
      }
      #pragma unroll
      for (int mi = 0; mi < 4; ++mi)
        #pragma unroll
        for (int ni = 0; ni < 8; ++ni)
          s[mi][ni] = MFMA16(af[mi], bv[ni], s[mi][ni]);
      __syncthreads();
      short* tmp = Acur; Acur = Anxt; Anxt = tmp;
    }
    // ---- softmax over the 128 cols, per row (row = 64w+16mi+4q+r) ----
    float mx[4][4], sm[4][4], rc[4][4];
    #pragma unroll
    for (int mi = 0; mi < 4; ++mi)
      #pragma unroll
      for (int r = 0; r < 4; ++r) {
        float m = s[mi][0][r];
        #pragma unroll
        for (int ni = 1; ni < 8; ++ni) m = fmaxf(m, s[mi][ni][r]);
        mx[mi][r] = m;
      }
    #pragma unroll
    for (int msk = 1; msk < 16; msk <<= 1)
      #pragma unroll
      for (int mi = 0; mi < 4; ++mi)
        #pragma unroll
        for (int r = 0; r < 4; ++r)
          mx[mi][r] = fmaxf(mx[mi][r], __shfl_xor(mx[mi][r], msk, 64));
    #pragma unroll
    for (int mi = 0; mi < 4; ++mi)
      #pragma unroll
      for (int r = 0; r < 4; ++r) sm[mi][r] = 0.f;
    #pragma unroll
    for (int mi = 0; mi < 4; ++mi)
      #pragma unroll
      for (int ni = 0; ni < 8; ++ni)
        #pragma unroll
        for (int r = 0; r < 4; ++r) {
          float p = exp2f((s[mi][ni][r] - mx[mi][r]) * SC);
          s[mi][ni][r] = p;
          sm[mi][r] += p;
        }
    #pragma unroll
    for (int msk = 1; msk < 16; msk <<= 1)
      #pragma unroll
      for (int mi = 0; mi < 4; ++mi)
        #pragma unroll
        for (int r = 0; r < 4; ++r)
          sm[mi][r] += __shfl_xor(sm[mi][r], msk, 64);
    #pragma unroll
    for (int mi = 0; mi < 4; ++mi)
      #pragma unroll
      for (int r = 0; r < 4; ++r) rc[mi][r] = __builtin_amdgcn_rcpf(sm[mi][r]);

    // ---- two i-halves: write aT (swizzled) then PV ----
    #pragma unroll
    for (int hf = 0; hf < 2; ++hf) {
      if ((w >> 1) == hf) {
        #pragma unroll
        for (int mi = 0; mi < 4; ++mi)
          #pragma unroll
          for (int ni = 0; ni < 8; ++ni) {
            s16x4 pk = { f2b(s[mi][ni][0] * rc[mi][0]), f2b(s[mi][ni][1] * rc[mi][1]),
                         f2b(s[mi][ni][2] * rc[mi][2]), f2b(s[mi][ni][3] * rc[mi][3]) };
            int j  = 16 * ni + rl;
            int ci = (w & 1) * 8 + 2 * mi + (q >> 1);
            *(s16x4*)((char*)aT + j * 256 + (ci ^ (j & 7)) * 16 + (q & 1) * 8) = pk;
          }
      }
      __syncthreads();
      #pragma unroll
      for (int kt = 0; kt < 4; ++kt) {
        bf16x8 pa[2], vv[4];
        #pragma unroll
        for (int mi = 0; mi < 2; ++mi) {
          int Rj = 32 * w + 16 * mi + rl;
          int ci = kt * 4 + q;
          pa[mi] = *(const bf16x8*)((const char*)aT + Rj * 256 + (ci ^ (Rj & 7)) * 16);
        }
        int ig = o * 256 + hf * 128 + kt * 32 + q * 8;
        #pragma unroll
        for (int nd = 0; nd < 4; ++nd)
          vv[nd] = *(const bf16x8*)(&Vb[(long)(16 * nd + rl) * 1024 + ig]);
        #pragma unroll
        for (int mi = 0; mi < 2; ++mi)
          #pragma unroll
          for (int nd = 0; nd < 4; ++nd)
            ot[mi][nd] = MFMA16(pa[mi], vv[nd], ot[mi][nd]);
      }
      __syncthreads();
    }
  }
  // epilogue: OT[b][c*128 + j][h*64 + d]
  short* OTb = OT + (long)(b * 1024 + c * 128) * 512 + h * 64;
  #pragma unroll
  for (int mi = 0; mi < 2; ++mi)
    #pragma unroll
    for (int nd = 0; nd < 4; ++nd)
      #pragma unroll
      for (int r = 0; r < 4; ++r) {
        int j = 32 * w + 16 * mi + 4 * q + r;
        int d = 16 * nd + rl;
        OTb[(long)j * 512 + d] = f2b(ot[mi][nd][r]);
      }
}

extern "C" void kernel_launch(void* const* d_in, const int* in_sizes, int n_in,
                              void* d_out, int out_size, void* d_ws, size_t ws_size,
                              hipStream_t stream)
{
  const float* x  = (const float*)d_in[0];
  const float* Wk = (const float*)d_in[1];
  const float* Wq = (const float*)d_in[2];
  const float* Wv = (const float*)d_in[3];
  const float* Wr = (const float*)d_in[4];
  const float* br = (const float*)d_in[5];
  float* out = (float*)d_out;

  char* ws = (char*)d_ws;
  short* Xbf = (short*)(ws + 0);         // [8][256][1024]
  short* XT  = (short*)(ws + 4194304);   // [8][1024][256]
  short* WqT = (short*)(ws + 8388608);   // [256][8192]
  short* Wkb = (short*)(ws + 12582912);  // [8192][256]
  short* Wvb = (short*)(ws + 16777216);  // [512][256]
  short* Wrb = (short*)(ws + 17039360);  // [256][512]
  short* Mb  = (short*)(ws + 17301504);  // [8][8][256][256]
  short* GTb = (short*)(ws + 25690112);  // [8][8][1024][256]  (= G^T per (b,h))
  short* Vbf = (short*)(ws + 59244544);  // [8][512][1024]
  short* OTb = (short*)(ws + 67633152);  // [8][1024][512]     (= O^T per b)

  // converts / transposes
  tcvt<<<dim3(16, 4, 8), 256, 0, stream>>>(x, Xbf, XT, 256, 1024, 262144L, 262144L, 262144L);
  tcvt<<<dim3(4, 128, 1), 256, 0, stream>>>(Wq, nullptr, WqT, 8192, 256, 0L, 0L, 0L);
  cvt_bf16<<<2048, 256, 0, stream>>>(Wk, Wkb, 2097152);
  cvt_bf16<<<128, 256, 0, stream>>>(Wv, Wvb, 131072);
  cvt_bf16<<<128, 256, 0, stream>>>(Wr, Wrb, 131072);

  // M[b,h] = X_b @ Wq_h            (256x256, K=1024)
  gemm_nt<false><<<dim3(2, 2, 64), 256, 0, stream>>>(Xbf, WqT, Mb, nullptr,
      256, 256, 1024, 1024, 8192, 256,
      262144L, 0L, 0L, 1024L, 524288L, 65536L, 8);
  // G^T[b,h] = X_b^T @ M (M as NxK) (1024x256, K=256)
  gemm_nt<false><<<dim3(2, 8, 64), 256, 0, stream>>>(XT, Mb, GTb, nullptr,
      1024, 256, 256, 256, 256, 256,
      262144L, 0L, 524288L, 65536L, 2097152L, 262144L, 8);
  // V[b] = Wv @ X_b                 (512x1024, K=256)
  gemm_nt<false><<<dim3(8, 4, 8), 256, 0, stream>>>(Wvb, XT, Vbf, nullptr,
      512, 1024, 256, 256, 256, 1024,
      0L, 0L, 262144L, 0L, 524288L, 0L, 1);
  // fused scores + chunk-softmax + PV  -> O^T
  attn_fused<<<512, 256, 0, stream>>>(Wkb, GTb, Vbf, OTb);
  // Y[b] = Wr @ O_b + br            (256x1024, K=512) -> d_out fp32
  gemm_nt<true><<<dim3(8, 2, 8), 256, 0, stream>>>(Wrb, OTb, out, br,
      256, 1024, 512, 512, 512, 1024,
      0L, 0L, 524288L, 0L, 262144L, 0L, 1);
}